// Round 13
// baseline (30.245 us; speedup 1.0000x reference)
//
#include <hip/hip_runtime.h>

#define MH 28
#define MW 28
#define CC 64
#define GG 4
#define NB 32

typedef float vf4 __attribute__((ext_vector_type(4)));

// XCD-bijective swizzle: 896 = 8 XCDs x 112 -> XCD k gets contiguous logical
// range = 4 complete batch images (contiguous DRAM streams, D1->D2 L2 reuse).
__device__ __forceinline__ int xcd_swizzle(int phys) {
    return (phys & 7) * 112 + (phys >> 3);
}

// ws layout:
//   [0, 3584)        : uint slotm[896]  (mask counts, written by D1)
//   [4096, 7680)     : uint slotd[896]  (dil counts, written by D2)
//   [8192, +25088)   : any-of-g map, uchar (B,28,28)

// ---------------- D1: pool + project + decide + WRITE MASK + mask count ----------------
// grid: 896 blocks (b, coarse row ch), 256 threads
__global__ __launch_bounds__(256, 3) void masker_d1(
    const float* __restrict__ x, const float* __restrict__ w,
    const float* __restrict__ bias, const float* __restrict__ gum,
    float* __restrict__ out_mask, unsigned char* __restrict__ anyb,
    unsigned int* __restrict__ slotm)
{
    const int blk = xcd_swizzle(blockIdx.x);      // = b*MH + ch
    const int b = blk / MH, ch = blk - (blk / MH) * MH;
    const int t = threadIdx.x;
    __shared__ float pooled[CC][MW];
    __shared__ float wlds[8 * CC];
    __shared__ float logits[8][MW];
    __shared__ float decf[GG][MW];
    __shared__ unsigned int sm[4];

    // ---- prefetch small operands ----
    float g0 = 0.f, g1 = 0.f, bo = 0.f;
    if (t < GG * MW) {
        int g = t / MW, cw = t - g * MW;
        g0 = gum[((((size_t)b * 2 + 0) * GG + g) * MH + ch) * MW + cw];
        g1 = gum[((((size_t)b * 2 + 1) * GG + g) * MH + ch) * MW + cw];
    }
    if (t < 8 * MW) bo = bias[t / MW];
    if (t < 128) ((float4*)wlds)[t] = ((const float4*)w)[t];

    // ---- all 28 NT float4 loads batched in flight, then reduce ----
    const float* xb = x + (size_t)b * CC * 12544 + (size_t)(4 * ch) * 112;
    vf4 r[7][4];
    #pragma unroll
    for (int k = 0; k < 7; ++k) {
        int p  = t + 256 * k;              // 0..1791 = c(64) x cw(28)
        int c  = p / MW;
        int cw = p - c * MW;
        const vf4* base = (const vf4*)(xb + (size_t)c * 12544 + 4 * cw);
        #pragma unroll
        for (int hh = 0; hh < 4; ++hh)
            r[k][hh] = __builtin_nontemporal_load(base + hh * 28);
    }
    #pragma unroll
    for (int k = 0; k < 7; ++k) {
        int p  = t + 256 * k;
        int c  = p / MW;
        int cw = p - c * MW;
        float s = 0.f;
        #pragma unroll
        for (int hh = 0; hh < 4; ++hh)
            s += r[k][hh].x + r[k][hh].y + r[k][hh].z + r[k][hh].w;
        pooled[c][cw] = s * 0.0625f;
    }
    __syncthreads();

    // ---- projection: 8 outputs x 28 cols ----
    if (t < 8 * MW) {
        int o = t / MW, cw = t - o * MW;
        float acc = bo;
        #pragma unroll
        for (int c = 0; c < CC; ++c)
            acc += pooled[c][cw] * wlds[o * CC + c];
        logits[o][cw] = acc;
    }
    __syncthreads();

    // ---- gumbel decision (T>0 scale argmax-invariant; ties -> idx 0) ----
    unsigned int local_m = 0;
    if (t < GG * MW) {
        int g = t / MW, cw = t - g * MW;
        float mv = (logits[g][cw] + g0 >= logits[g + 4][cw] + g1) ? 1.f : 0.f;
        decf[g][cw] = mv;
        local_m = (unsigned int)mv;
    }
    __syncthreads();

    if (t < MW) {
        float a = fmaxf(fmaxf(decf[0][t], decf[1][t]), fmaxf(decf[2][t], decf[3][t]));
        anyb[(size_t)blk * MW + t] = (unsigned char)a;
    }

    // ---- mask output: 1792 = g(4) x hh(4) x w(112), NT stores ----
    #pragma unroll
    for (int k = 0; k < 7; ++k) {
        int idx = t + 256 * k;
        int g   = idx / 448;
        int rem = idx - g * 448;
        int hh  = rem / 112;
        int wfi = rem - hh * 112;
        float mv = decf[g][wfi >> 2];
        size_t o = (((size_t)b * GG + g) * 112 + (4 * ch + hh)) * 112 + wfi;
        __builtin_nontemporal_store(mv, &out_mask[o]);
    }

    // ---- mask count reduce -> slotm ----
    #pragma unroll
    for (int off = 32; off; off >>= 1)
        local_m += __shfl_down(local_m, off);
    if ((t & 63) == 0) sm[t >> 6] = local_m;
    __syncthreads();
    if (t == 0) slotm[blk] = sm[0] + sm[1] + sm[2] + sm[3];
}

// ---------------- D2: dilate + write out_dil + dil count ----------------
// grid: 896 blocks, 256 threads; same swizzle -> anyb is local-L2 hot
__global__ __launch_bounds__(256) void masker_d2(
    const unsigned char* __restrict__ anyb,
    float* __restrict__ out_dil, unsigned int* __restrict__ slotd)
{
    const int blk = xcd_swizzle(blockIdx.x);
    const int b = blk / MH, ch = blk - (blk / MH) * MH;
    const int t = threadIdx.x;
    __shared__ float R[3][MW + 2];
    __shared__ unsigned int sd[4];

    if (t < MW) {
        float a  = (float)anyb[(size_t)blk * MW + t];
        float am = (ch > 0)      ? (float)anyb[(size_t)(blk - 1) * MW + t] : 0.f;
        float ap = (ch < MH - 1) ? (float)anyb[(size_t)(blk + 1) * MW + t] : 0.f;
        R[0][t + 1] = fmaxf(a, am);
        R[1][t + 1] = a;
        R[2][t + 1] = fmaxf(a, ap);
    }
    if (t < 3) { R[t][0] = 0.f; R[t][MW + 1] = 0.f; }
    __syncthreads();

    unsigned int local_d = 0;
    #pragma unroll
    for (int k = 0; k < 7; ++k) {
        int idx = t + 256 * k;             // g(4) x hh(4) x w(112)
        int g   = idx / 448;
        int rem = idx - g * 448;
        int hh  = rem / 112;
        int wfi = rem - hh * 112;
        int cw  = wfi >> 2;
        int wm  = wfi & 3;
        int rv  = (hh == 0) ? 0 : (hh == 3 ? 2 : 1);
        float d;
        if (wm == 0)      d = fmaxf(R[rv][cw],     R[rv][cw + 1]);
        else if (wm == 3) d = fmaxf(R[rv][cw + 1], R[rv][cw + 2]);
        else              d = R[rv][cw + 1];
        size_t o = (((size_t)b * GG + g) * 112 + (4 * ch + hh)) * 112 + wfi;
        __builtin_nontemporal_store(d, &out_dil[o]);
        local_d += (d > 0.5f) ? 1u : 0u;
    }

    #pragma unroll
    for (int off = 32; off; off >>= 1)
        local_d += __shfl_down(local_d, off);
    if ((t & 63) == 0) sd[t >> 6] = local_d;
    __syncthreads();
    if (t == 0) slotd[blk] = sd[0] + sd[1] + sd[2] + sd[3];
}

// ---------------- D3: reduce 2x896 slots -> scalars ----------------
__global__ __launch_bounds__(256) void masker_d3(
    const unsigned int* __restrict__ slotm,
    const unsigned int* __restrict__ slotd,
    float* __restrict__ out_scalars)
{
    int t = threadIdx.x;
    unsigned int m = 0, d = 0;
    for (int i = t; i < NB * MH; i += 256) { m += slotm[i]; d += slotd[i]; }
    #pragma unroll
    for (int off = 32; off; off >>= 1) {
        m += __shfl_down(m, off);
        d += __shfl_down(d, off);
    }
    __shared__ unsigned int sm[4], sd[4];
    if ((t & 63) == 0) { sm[t >> 6] = m; sd[t >> 6] = d; }
    __syncthreads();
    if (t == 0) {
        out_scalars[0] = (float)(sm[0] + sm[1] + sm[2] + sm[3]) / 100352.0f;   // B*G*28*28
        out_scalars[1] = (float)(sd[0] + sd[1] + sd[2] + sd[3]) / 1605632.0f;  // B*G*112*112
        out_scalars[2] = 501760.0f;                                            // flops const
    }
}

extern "C" void kernel_launch(void* const* d_in, const int* in_sizes, int n_in,
                              void* d_out, int out_size, void* d_ws, size_t ws_size,
                              hipStream_t stream) {
    const float* x    = (const float*)d_in[0];
    const float* w    = (const float*)d_in[1];
    const float* bias = (const float*)d_in[2];
    const float* gum  = (const float*)d_in[3];

    float* out = (float*)d_out;
    const size_t n_mask = (size_t)NB * GG * 112 * 112;   // 1,605,632

    unsigned int*  slotm = (unsigned int*)d_ws;
    unsigned int*  slotd = (unsigned int*)((char*)d_ws + 4096);
    unsigned char* anyb  = (unsigned char*)d_ws + 8192;

    dim3 grid(NB * MH);
    masker_d1<<<grid, 256, 0, stream>>>(x, w, bias, gum, out, anyb, slotm);
    masker_d2<<<grid, 256, 0, stream>>>(anyb, out + n_mask, slotd);
    masker_d3<<<1, 256, 0, stream>>>(slotm, slotd, out + 2 * n_mask);
}

// Round 14
// 27.999 us; speedup vs baseline: 1.0802x; 1.0802x over previous
//
#include <hip/hip_runtime.h>

#define MH 28
#define MW 28
#define CC 64
#define GG 4
#define NB 32
#define RPB 2            // coarse rows per D1 block

typedef float vf4 __attribute__((ext_vector_type(4)));

// XCD-bijective swizzles (grid = 8 * k exactly)
__device__ __forceinline__ int xcd_swz896(int phys) {   // 896 = 8*112
    return (phys & 7) * 112 + (phys >> 3);
}
__device__ __forceinline__ int xcd_swz448(int phys) {   // 448 = 8*56
    return (phys & 7) * 56 + (phys >> 3);
}

// ws layout:
//   [0, 7168)           : uint2 slots[896] (overwritten every call, no init)
//   [8192, +100352)     : coarse mask, uchar (B,G,28,28)
//   [108544, +25088)    : any-of-g map, uchar (B,28,28)

// ---------------- D1: pool + project + decide, 2 coarse rows per block ----------------
// grid: 448 blocks (b, row-pair rp), 256 threads
// Per channel, block reads 8 consecutive fine rows = 3584 B contiguous.
__global__ __launch_bounds__(256, 3) void masker_d1(
    const float* __restrict__ x, const float* __restrict__ w,
    const float* __restrict__ bias, const float* __restrict__ gum,
    unsigned char* __restrict__ coarse, unsigned char* __restrict__ anyb)
{
    const int blk = xcd_swz448(blockIdx.x);       // = b*14 + rp
    const int b = blk / 14, rp = blk - (blk / 14) * 14;
    const int chA = 2 * rp, chB = 2 * rp + 1;
    const int t = threadIdx.x;

    __shared__ float pooled[RPB][CC][MW];         // 14 KB
    __shared__ float wlds[8 * CC];
    __shared__ float logits[RPB][8][MW];
    __shared__ unsigned char mlds[RPB][GG][MW];

    // ---- prefetch small operands (both rows) ----
    float g0a = 0.f, g1a = 0.f, g0b = 0.f, g1b = 0.f, bo = 0.f;
    if (t < GG * MW) {
        int g = t / MW, cw = t - g * MW;
        g0a = gum[((((size_t)b * 2 + 0) * GG + g) * MH + chA) * MW + cw];
        g1a = gum[((((size_t)b * 2 + 1) * GG + g) * MH + chA) * MW + cw];
        g0b = gum[((((size_t)b * 2 + 0) * GG + g) * MH + chB) * MW + cw];
        g1b = gum[((((size_t)b * 2 + 1) * GG + g) * MH + chB) * MW + cw];
    }
    if (t < 8 * MW) bo = bias[t / MW];
    if (t < 128) ((float4*)wlds)[t] = ((const float4*)w)[t];

    // ---- two batches of 28 NT float4 loads (one per coarse row) ----
    const float* xb = x + (size_t)b * CC * 12544 + (size_t)(8 * rp) * 112;
    #pragma unroll
    for (int r = 0; r < RPB; ++r) {
        vf4 rr[7][4];
        #pragma unroll
        for (int k = 0; k < 7; ++k) {
            int p  = t + 256 * k;              // 0..1791 = c(64) x cw(28)
            int c  = p / MW;
            int cw = p - c * MW;
            const vf4* base = (const vf4*)(xb + (size_t)c * 12544
                                              + (size_t)(4 * r) * 112 + 4 * cw);
            #pragma unroll
            for (int hh = 0; hh < 4; ++hh)
                rr[k][hh] = __builtin_nontemporal_load(base + hh * 28);
        }
        #pragma unroll
        for (int k = 0; k < 7; ++k) {
            int p  = t + 256 * k;
            int c  = p / MW;
            int cw = p - c * MW;
            float s = 0.f;
            #pragma unroll
            for (int hh = 0; hh < 4; ++hh)
                s += rr[k][hh].x + rr[k][hh].y + rr[k][hh].z + rr[k][hh].w;
            pooled[r][c][cw] = s * 0.0625f;
        }
    }
    __syncthreads();

    // ---- projection: 8 outputs x 28 cols, both rows ----
    if (t < 8 * MW) {
        int o = t / MW, cw = t - o * MW;
        float accA = bo, accB = bo;
        #pragma unroll
        for (int c = 0; c < CC; ++c) {
            float wv = wlds[o * CC + c];
            accA += pooled[0][c][cw] * wv;
            accB += pooled[1][c][cw] * wv;
        }
        logits[0][o][cw] = accA;
        logits[1][o][cw] = accB;
    }
    __syncthreads();

    // ---- gumbel decision (T>0 scale argmax-invariant; ties -> idx 0) ----
    if (t < GG * MW) {
        int g = t / MW, cw = t - g * MW;
        unsigned char mvA = (logits[0][g][cw] + g0a >= logits[0][g + 4][cw] + g1a) ? 1u : 0u;
        unsigned char mvB = (logits[1][g][cw] + g0b >= logits[1][g + 4][cw] + g1b) ? 1u : 0u;
        mlds[0][g][cw] = mvA;
        mlds[1][g][cw] = mvB;
        coarse[(((size_t)b * GG + g) * MH + chA) * MW + cw] = mvA;
        coarse[(((size_t)b * GG + g) * MH + chB) * MW + cw] = mvB;
    }
    __syncthreads();
    if (t < 2 * MW) {
        int r = t / MW, cw = t - r * MW;
        unsigned char a = mlds[r][0][cw] | mlds[r][1][cw] | mlds[r][2][cw] | mlds[r][3][cw];
        anyb[((size_t)b * MH + (2 * rp + r)) * MW + cw] = a;
    }
}

// ---------------- D2: upsample + dilate + outputs + per-block counts ----------------
// grid: 896 blocks, 256 threads (identical to R12)
__global__ __launch_bounds__(256) void masker_d2(
    const unsigned char* __restrict__ coarse,
    const unsigned char* __restrict__ anyb,
    float* __restrict__ out_mask, float* __restrict__ out_dil,
    uint2* __restrict__ slots)
{
    const int blk = xcd_swz896(blockIdx.x);
    int b = blk / MH, ch = blk - (blk / MH) * MH, t = threadIdx.x;
    __shared__ float carr[GG][MW];
    __shared__ float R[3][MW + 2];
    __shared__ unsigned int sm[4], sd[4];

    unsigned int local_m = 0;
    if (t < GG * MW) {
        int g = t / MW, cw = t - g * MW;
        unsigned char mv = coarse[(((size_t)b * GG + g) * MH + ch) * MW + cw];
        carr[g][cw] = (float)mv;
        local_m = mv;
    }
    if (t < MW) {
        float a  = (float)anyb[((size_t)b * MH + ch) * MW + t];
        float am = (ch > 0)      ? (float)anyb[((size_t)b * MH + ch - 1) * MW + t] : 0.f;
        float ap = (ch < MH - 1) ? (float)anyb[((size_t)b * MH + ch + 1) * MW + t] : 0.f;
        R[0][t + 1] = fmaxf(a, am);
        R[1][t + 1] = a;
        R[2][t + 1] = fmaxf(a, ap);
    }
    if (t < 3) { R[t][0] = 0.f; R[t][MW + 1] = 0.f; }
    __syncthreads();

    unsigned int local_d = 0;
    #pragma unroll
    for (int k = 0; k < 7; ++k) {
        int idx = t + 256 * k;             // g(4) x hh(4) x w(112)
        int g   = idx / 448;
        int rem = idx - g * 448;
        int hh  = rem / 112;
        int wfi = rem - hh * 112;
        int cw  = wfi >> 2;
        int wm  = wfi & 3;
        int rv  = (hh == 0) ? 0 : (hh == 3 ? 2 : 1);
        float d;
        if (wm == 0)      d = fmaxf(R[rv][cw],     R[rv][cw + 1]);
        else if (wm == 3) d = fmaxf(R[rv][cw + 1], R[rv][cw + 2]);
        else              d = R[rv][cw + 1];
        float mv = carr[g][cw];
        size_t o = (((size_t)b * GG + g) * 112 + (4 * ch + hh)) * 112 + wfi;
        __builtin_nontemporal_store(mv, &out_mask[o]);
        __builtin_nontemporal_store(d,  &out_dil[o]);
        local_d += (d > 0.5f) ? 1u : 0u;
    }

    // dual wave reduction, no atomics
    #pragma unroll
    for (int off = 32; off; off >>= 1) {
        local_m += __shfl_down(local_m, off);
        local_d += __shfl_down(local_d, off);
    }
    if ((t & 63) == 0) { sm[t >> 6] = local_m; sd[t >> 6] = local_d; }
    __syncthreads();
    if (t == 0) {
        uint2 v;
        v.x = sm[0] + sm[1] + sm[2] + sm[3];
        v.y = sd[0] + sd[1] + sd[2] + sd[3];
        slots[blk] = v;                    // overwrite: no init required
    }
}

// ---------------- D3: reduce 896 slots -> scalars ----------------
__global__ __launch_bounds__(256) void masker_d3(
    const uint2* __restrict__ slots, float* __restrict__ out_scalars)
{
    int t = threadIdx.x;
    unsigned int m = 0, d = 0;
    for (int i = t; i < NB * MH; i += 256) { uint2 v = slots[i]; m += v.x; d += v.y; }
    #pragma unroll
    for (int off = 32; off; off >>= 1) {
        m += __shfl_down(m, off);
        d += __shfl_down(d, off);
    }
    __shared__ unsigned int sm[4], sd[4];
    if ((t & 63) == 0) { sm[t >> 6] = m; sd[t >> 6] = d; }
    __syncthreads();
    if (t == 0) {
        out_scalars[0] = (float)(sm[0] + sm[1] + sm[2] + sm[3]) / 100352.0f;   // B*G*28*28
        out_scalars[1] = (float)(sd[0] + sd[1] + sd[2] + sd[3]) / 1605632.0f;  // B*G*112*112
        out_scalars[2] = 501760.0f;                                            // flops const
    }
}

extern "C" void kernel_launch(void* const* d_in, const int* in_sizes, int n_in,
                              void* d_out, int out_size, void* d_ws, size_t ws_size,
                              hipStream_t stream) {
    const float* x    = (const float*)d_in[0];
    const float* w    = (const float*)d_in[1];
    const float* bias = (const float*)d_in[2];
    const float* gum  = (const float*)d_in[3];

    float* out = (float*)d_out;
    const size_t n_mask = (size_t)NB * GG * 112 * 112;   // 1,605,632

    uint2*         slots  = (uint2*)d_ws;
    unsigned char* coarse = (unsigned char*)d_ws + 8192;
    unsigned char* anyb   = (unsigned char*)d_ws + 8192 + 100352;

    masker_d1<<<dim3(NB * MH / RPB), 256, 0, stream>>>(x, w, bias, gum, coarse, anyb);
    masker_d2<<<dim3(NB * MH), 256, 0, stream>>>(coarse, anyb, out, out + n_mask, slots);
    masker_d3<<<1, 256, 0, stream>>>(slots, out + 2 * n_mask);
}

// Round 15
// 27.656 us; speedup vs baseline: 1.0936x; 1.0124x over previous
//
#include <hip/hip_runtime.h>

#define MH 28
#define MW 28
#define CC 64
#define GG 4
#define NB 32
#define RPB 2            // coarse rows per D1 block

typedef float vf4 __attribute__((ext_vector_type(4)));

// XCD-bijective swizzles (grid = 8 * k exactly)
__device__ __forceinline__ int xcd_swz896(int phys) { return (phys & 7) * 112 + (phys >> 3); }
__device__ __forceinline__ int xcd_swz448(int phys) { return (phys & 7) * 56  + (phys >> 3); }

// ws layout:
//   [0, 7168)           : uint2 slots[896] (overwritten every call, no init)
//   [8192, +100352)     : coarse mask, uchar (B,G,28,28)
//   [108544, +25088)    : any-of-g map, uchar (B,28,28)

// ---------------- D1: pool + project + decide, flat-coalesced loads ----------------
// grid: 448 blocks (b, row-pair rp), 256 threads
// Flat slab-major index: every wave instruction reads 1024 B fully contiguous.
// Pooling = in-register horizontal sum + LDS cross-row add.
__global__ __launch_bounds__(256, 3) void masker_d1(
    const float* __restrict__ x, const float* __restrict__ w,
    const float* __restrict__ bias, const float* __restrict__ gum,
    unsigned char* __restrict__ coarse, unsigned char* __restrict__ anyb)
{
    const int blk = xcd_swz448(blockIdx.x);       // = b*14 + rp
    const int b = blk / 14, rp = blk - (blk / 14) * 14;
    const int chA = 2 * rp, chB = 2 * rp + 1;
    const int t = threadIdx.x;

    __shared__ float rowsum[32 * 8 * MW];         // [c_local][fine row r8][cw]  28.7 KB
    __shared__ float pooled[RPB][CC][MW];         // 14.3 KB
    __shared__ float wlds[8 * CC];
    __shared__ float logits[RPB][8][MW];
    __shared__ unsigned char mlds[RPB][GG][MW];

    // ---- prefetch small operands (both rows) ----
    float g0a = 0.f, g1a = 0.f, g0b = 0.f, g1b = 0.f, bo = 0.f;
    if (t < GG * MW) {
        int g = t / MW, cw = t - g * MW;
        g0a = gum[((((size_t)b * 2 + 0) * GG + g) * MH + chA) * MW + cw];
        g1a = gum[((((size_t)b * 2 + 1) * GG + g) * MH + chA) * MW + cw];
        g0b = gum[((((size_t)b * 2 + 0) * GG + g) * MH + chB) * MW + cw];
        g1b = gum[((((size_t)b * 2 + 1) * GG + g) * MH + chB) * MW + cw];
    }
    if (t < 8 * MW) bo = bias[t / MW];
    if (t < 128) ((float4*)wlds)[t] = ((const float4*)w)[t];

    // x region: 64 slabs (one per channel) of 8 fine rows x 112 = 3584 B each
    const float* xb = x + (size_t)b * CC * 12544 + (size_t)(8 * rp) * 112;

    #pragma unroll
    for (int h = 0; h < 2; ++h) {                 // channel halves [h*32, h*32+32)
        // ---- flat-coalesced NT loads: 28 float4/thread, 1024 B contiguous per wave instr ----
        vf4 r[28];
        #pragma unroll
        for (int j = 0; j < 28; ++j) {
            int f = t + 256 * j;                  // 0..7167 over half
            int s = f / 224;                      // slab (channel) within half
            int off = f - s * 224;                // float4 offset inside slab
            r[j] = __builtin_nontemporal_load(
                (const vf4*)(xb + (size_t)(h * 32 + s) * 12544) + off);
        }
        // ---- horizontal sums -> rowsum[c][r8][cw] (flat addr = f: conflict-free) ----
        #pragma unroll
        for (int j = 0; j < 28; ++j) {
            int f = t + 256 * j;
            rowsum[f] = r[j].x + r[j].y + r[j].z + r[j].w;
        }
        __syncthreads();
        // ---- vertical sums: 1792 cells = c(32) x r(2) x cw(28), 7/thread ----
        #pragma unroll
        for (int k = 0; k < 7; ++k) {
            int idx = t + 256 * k;
            int c_l = idx / 56;
            int rem = idx - c_l * 56;
            int rr  = rem / MW;
            int cw  = rem - rr * MW;
            const float* rs = &rowsum[c_l * 224 + rr * 4 * MW + cw];
            pooled[rr][h * 32 + c_l][cw] =
                (rs[0] + rs[MW] + rs[2 * MW] + rs[3 * MW]) * 0.0625f;
        }
        __syncthreads();
    }

    // ---- projection: 8 outputs x 28 cols, both rows ----
    if (t < 8 * MW) {
        int o = t / MW, cw = t - o * MW;
        float accA = bo, accB = bo;
        #pragma unroll
        for (int c = 0; c < CC; ++c) {
            float wv = wlds[o * CC + c];
            accA += pooled[0][c][cw] * wv;
            accB += pooled[1][c][cw] * wv;
        }
        logits[0][o][cw] = accA;
        logits[1][o][cw] = accB;
    }
    __syncthreads();

    // ---- gumbel decision (T>0 scale argmax-invariant; ties -> idx 0) ----
    if (t < GG * MW) {
        int g = t / MW, cw = t - g * MW;
        unsigned char mvA = (logits[0][g][cw] + g0a >= logits[0][g + 4][cw] + g1a) ? 1u : 0u;
        unsigned char mvB = (logits[1][g][cw] + g0b >= logits[1][g + 4][cw] + g1b) ? 1u : 0u;
        mlds[0][g][cw] = mvA;
        mlds[1][g][cw] = mvB;
        coarse[(((size_t)b * GG + g) * MH + chA) * MW + cw] = mvA;
        coarse[(((size_t)b * GG + g) * MH + chB) * MW + cw] = mvB;
    }
    __syncthreads();
    if (t < 2 * MW) {
        int r = t / MW, cw = t - r * MW;
        unsigned char a = mlds[r][0][cw] | mlds[r][1][cw] | mlds[r][2][cw] | mlds[r][3][cw];
        anyb[((size_t)b * MH + (2 * rp + r)) * MW + cw] = a;
    }
}

// ---------------- D2: upsample + dilate + outputs + per-block counts ----------------
// grid: 896 blocks, 256 threads (identical to R12/R14)
__global__ __launch_bounds__(256) void masker_d2(
    const unsigned char* __restrict__ coarse,
    const unsigned char* __restrict__ anyb,
    float* __restrict__ out_mask, float* __restrict__ out_dil,
    uint2* __restrict__ slots)
{
    const int blk = xcd_swz896(blockIdx.x);
    int b = blk / MH, ch = blk - (blk / MH) * MH, t = threadIdx.x;
    __shared__ float carr[GG][MW];
    __shared__ float R[3][MW + 2];
    __shared__ unsigned int sm[4], sd[4];

    unsigned int local_m = 0;
    if (t < GG * MW) {
        int g = t / MW, cw = t - g * MW;
        unsigned char mv = coarse[(((size_t)b * GG + g) * MH + ch) * MW + cw];
        carr[g][cw] = (float)mv;
        local_m = mv;
    }
    if (t < MW) {
        float a  = (float)anyb[((size_t)b * MH + ch) * MW + t];
        float am = (ch > 0)      ? (float)anyb[((size_t)b * MH + ch - 1) * MW + t] : 0.f;
        float ap = (ch < MH - 1) ? (float)anyb[((size_t)b * MH + ch + 1) * MW + t] : 0.f;
        R[0][t + 1] = fmaxf(a, am);
        R[1][t + 1] = a;
        R[2][t + 1] = fmaxf(a, ap);
    }
    if (t < 3) { R[t][0] = 0.f; R[t][MW + 1] = 0.f; }
    __syncthreads();

    unsigned int local_d = 0;
    #pragma unroll
    for (int k = 0; k < 7; ++k) {
        int idx = t + 256 * k;             // g(4) x hh(4) x w(112)
        int g   = idx / 448;
        int rem = idx - g * 448;
        int hh  = rem / 112;
        int wfi = rem - hh * 112;
        int cw  = wfi >> 2;
        int wm  = wfi & 3;
        int rv  = (hh == 0) ? 0 : (hh == 3 ? 2 : 1);
        float d;
        if (wm == 0)      d = fmaxf(R[rv][cw],     R[rv][cw + 1]);
        else if (wm == 3) d = fmaxf(R[rv][cw + 1], R[rv][cw + 2]);
        else              d = R[rv][cw + 1];
        float mv = carr[g][cw];
        size_t o = (((size_t)b * GG + g) * 112 + (4 * ch + hh)) * 112 + wfi;
        __builtin_nontemporal_store(mv, &out_mask[o]);
        __builtin_nontemporal_store(d,  &out_dil[o]);
        local_d += (d > 0.5f) ? 1u : 0u;
    }

    #pragma unroll
    for (int off = 32; off; off >>= 1) {
        local_m += __shfl_down(local_m, off);
        local_d += __shfl_down(local_d, off);
    }
    if ((t & 63) == 0) { sm[t >> 6] = local_m; sd[t >> 6] = local_d; }
    __syncthreads();
    if (t == 0) {
        uint2 v;
        v.x = sm[0] + sm[1] + sm[2] + sm[3];
        v.y = sd[0] + sd[1] + sd[2] + sd[3];
        slots[blk] = v;
    }
}

// ---------------- D3: reduce 896 slots -> scalars ----------------
__global__ __launch_bounds__(256) void masker_d3(
    const uint2* __restrict__ slots, float* __restrict__ out_scalars)
{
    int t = threadIdx.x;
    unsigned int m = 0, d = 0;
    for (int i = t; i < NB * MH; i += 256) { uint2 v = slots[i]; m += v.x; d += v.y; }
    #pragma unroll
    for (int off = 32; off; off >>= 1) {
        m += __shfl_down(m, off);
        d += __shfl_down(d, off);
    }
    __shared__ unsigned int sm[4], sd[4];
    if ((t & 63) == 0) { sm[t >> 6] = m; sd[t >> 6] = d; }
    __syncthreads();
    if (t == 0) {
        out_scalars[0] = (float)(sm[0] + sm[1] + sm[2] + sm[3]) / 100352.0f;   // B*G*28*28
        out_scalars[1] = (float)(sd[0] + sd[1] + sd[2] + sd[3]) / 1605632.0f;  // B*G*112*112
        out_scalars[2] = 501760.0f;                                            // flops const
    }
}

extern "C" void kernel_launch(void* const* d_in, const int* in_sizes, int n_in,
                              void* d_out, int out_size, void* d_ws, size_t ws_size,
                              hipStream_t stream) {
    const float* x    = (const float*)d_in[0];
    const float* w    = (const float*)d_in[1];
    const float* bias = (const float*)d_in[2];
    const float* gum  = (const float*)d_in[3];

    float* out = (float*)d_out;
    const size_t n_mask = (size_t)NB * GG * 112 * 112;   // 1,605,632

    uint2*         slots  = (uint2*)d_ws;
    unsigned char* coarse = (unsigned char*)d_ws + 8192;
    unsigned char* anyb   = (unsigned char*)d_ws + 8192 + 100352;

    masker_d1<<<dim3(NB * MH / RPB), 256, 0, stream>>>(x, w, bias, gum, coarse, anyb);
    masker_d2<<<dim3(NB * MH), 256, 0, stream>>>(coarse, anyb, out, out + n_mask, slots);
    masker_d3<<<1, 256, 0, stream>>>(slots, out + 2 * n_mask);
}